// Round 2
// baseline (640.192 us; speedup 1.0000x reference)
//
#include <hip/hip_runtime.h>
#include <hip/hip_bf16.h>

typedef unsigned short u16;
typedef __attribute__((ext_vector_type(8))) short short8;
typedef __attribute__((ext_vector_type(4))) float floatx4;

#define DEVI static __device__ __forceinline__

DEVI float bf2f(u16 b) { return __uint_as_float(((unsigned)b) << 16); }
DEVI u16 f2bf(float f) {
  __hip_bfloat16 h = __float2bfloat16(f);
  u16 u; __builtin_memcpy(&u, &h, 2); return u;
}

// ---------------- weight transpose + fp32->bf16: dst[C][R] = bf16(src[R][C]^T) ----------------
struct TransArgs {
  const float* src[10];
  u16* dst[10];
  int R[10];
  int C[10];
};

__global__ __launch_bounds__(256) void transpose_k(TransArgs t) {
  const int z = blockIdx.z;
  const float* __restrict__ src = t.src[z];
  u16* __restrict__ dst = t.dst[z];
  const int R = t.R[z], C = t.C[z];
  const int c0 = blockIdx.x * 32, r0 = blockIdx.y * 32;
  if (c0 >= C || r0 >= R) return;
  __shared__ float tile[32][33];
  const int tx = threadIdx.x & 31, ty = threadIdx.x >> 5;
  for (int i = ty; i < 32; i += 8)
    tile[i][tx] = src[(size_t)(r0 + i) * C + c0 + tx];
  __syncthreads();
  for (int i = ty; i < 32; i += 8)
    dst[(size_t)(c0 + i) * R + r0 + tx] = f2bf(tile[tx][i]);
}

// ------------- GEMM: C[M][N] = act(A[M][K] @ W + bias), WT[N][K] bf16 given -------------
struct GemmArgs {
  const void* A[3];      // fp32 if a_f32 else bf16
  const u16* WT[3];      // bf16
  const float* bias[3];  // fp32
  void* C[3];            // fp32 if c_f32 else bf16
};

__global__ __launch_bounds__(256) void gemm_bias_act(GemmArgs ga, int M, int N, int K,
                                                     int relu, int a_f32, int c_f32) {
  const int z = blockIdx.z;
  const void* __restrict__ A = ga.A[z];
  const u16* __restrict__ WT = ga.WT[z];
  const float* __restrict__ bias = ga.bias[z];
  void* __restrict__ C = ga.C[z];

  // +8 bf16 pad -> row pitch 144B (16B aligned)
  __shared__ u16 As[64][72];
  __shared__ u16 Bs[64][72];

  const int tid = threadIdx.x;
  const int lane = tid & 63;
  const int wave = tid >> 6;
  const int wm = wave >> 1, wn = wave & 1;
  const int mb = blockIdx.y, nb = blockIdx.x;

  floatx4 acc0 = {0.f, 0.f, 0.f, 0.f}, acc1 = acc0, acc2 = acc0, acc3 = acc0;

  const int sr = tid >> 3;        // 0..31
  const int sc = (tid & 7) * 8;   // 0..56 (granule of 8 elements)

  for (int k0 = 0; k0 < K; k0 += 64) {
    __syncthreads();
#pragma unroll
    for (int it = 0; it < 2; ++it) {
      const int rr = sr + it * 32;
      if (a_f32) {
        const float* Af = (const float*)A;
        const float4 f0 = *(const float4*)(Af + (size_t)(mb * 64 + rr) * K + k0 + sc);
        const float4 f1 = *(const float4*)(Af + (size_t)(mb * 64 + rr) * K + k0 + sc + 4);
        u16 tmp[8] = {f2bf(f0.x), f2bf(f0.y), f2bf(f0.z), f2bf(f0.w),
                      f2bf(f1.x), f2bf(f1.y), f2bf(f1.z), f2bf(f1.w)};
        int4 t; __builtin_memcpy(&t, tmp, 16);
        *(int4*)&As[rr][sc] = t;
      } else {
        const u16* Ab = (const u16*)A;
        *(int4*)&As[rr][sc] = *(const int4*)(Ab + (size_t)(mb * 64 + rr) * K + k0 + sc);
      }
      *(int4*)&Bs[rr][sc] = *(const int4*)(WT + (size_t)(nb * 64 + rr) * K + k0 + sc);
    }
    __syncthreads();
#pragma unroll
    for (int ks = 0; ks < 2; ++ks) {
      const int koff = ks * 32 + (lane >> 4) * 8;   // A[m=lane&15][k=quad*8+j]
      const int am = wm * 32 + (lane & 15);
      const int bn = wn * 32 + (lane & 15);
      short8 a0 = *(const short8*)&As[am][koff];
      short8 a1 = *(const short8*)&As[am + 16][koff];
      short8 b0 = *(const short8*)&Bs[bn][koff];
      short8 b1 = *(const short8*)&Bs[bn + 16][koff];
      acc0 = __builtin_amdgcn_mfma_f32_16x16x32_bf16(a0, b0, acc0, 0, 0, 0);
      acc1 = __builtin_amdgcn_mfma_f32_16x16x32_bf16(a0, b1, acc1, 0, 0, 0);
      acc2 = __builtin_amdgcn_mfma_f32_16x16x32_bf16(a1, b0, acc2, 0, 0, 0);
      acc3 = __builtin_amdgcn_mfma_f32_16x16x32_bf16(a1, b1, acc3, 0, 0, 0);
    }
  }

  // C/D layout: col = lane&15, row = (lane>>4)*4 + reg (m89/m91 verified)
  const int colb = nb * 64 + wn * 32 + (lane & 15);
  const int rowb = mb * 64 + wm * 32 + (lane >> 4) * 4;
  const floatx4 accs[4] = {acc0, acc1, acc2, acc3};
#pragma unroll
  for (int mg = 0; mg < 2; ++mg) {
#pragma unroll
    for (int ng = 0; ng < 2; ++ng) {
      const int col = colb + ng * 16;
      const float bv = bias[col];
      const floatx4 v = accs[mg * 2 + ng];
#pragma unroll
      for (int r = 0; r < 4; ++r) {
        const int row = rowb + mg * 16 + r;
        float x = v[r] + bv;
        if (relu) x = fmaxf(x, 0.f);
        if (c_f32) ((float*)C)[(size_t)row * N + col] = x;
        else       ((u16*)C)[(size_t)row * N + col] = f2bf(x);
      }
    }
  }
}

// ---------------- fused attention (fp32 math, bf16 storage) ----------------
// out_pre[b,j,f] = sum_i softmax_h(-0.5*d8^2)[f%8] * V[b,i,f]
// d8[h] = sum_{f%8==h} |K[b,i,f]-Q[b,j,f]|
__global__ __launch_bounds__(256) void attn_kernel(const u16* __restrict__ Km,
                                                   const u16* __restrict__ Qm,
                                                   const u16* __restrict__ Vm,
                                                   u16* __restrict__ out_pre) {
  // 16B granules, XOR-swizzled by (row&7): bank-balanced for both
  // lane=key (phase 1) and lane=granule (phase 2) access patterns.
  __shared__ alignas(16) u16 Qs[16 * 512];
  __shared__ alignas(16) u16 Ks[16 * 512];
  __shared__ alignas(16) u16 Vs[16 * 512];
  __shared__ alignas(16) float attn_s[16 * 16 * 8];   // [q_local][key][h]

  const int tid = threadIdx.x;
  const int lane = tid & 63;
  const int wave = tid >> 6;
  const int bid = blockIdx.x;
  const int b = bid >> 6;
  const int j0 = (bid & 63) * 16;

  // stage 16 Q rows once (raw bf16, swizzled granules)
  for (int s = tid; s < 1024; s += 256) {
    const int r = s >> 6, gg = s & 63;
    const int4 raw = *(const int4*)(Qm + ((size_t)(b * 1024 + j0 + r) * 512) + gg * 8);
    *(int4*)(Qs + r * 512 + ((gg ^ (r & 7)) * 8)) = raw;
  }

  const int key = lane & 15;
  const int quad = lane >> 4;             // phase-1: which of this wave's 4 queries
  const int q_local = wave * 4 + quad;
  const int ksw = key & 7;
  const int qsw = q_local & 7;
  const int g = lane;                     // phase-2 feature granule

  int koff8[8], qoff8[8], voff8[8];
#pragma unroll
  for (int t = 0; t < 8; ++t) {
    koff8[t] = key * 512 + ((ksw ^ t) * 8);
    qoff8[t] = q_local * 512 + ((qsw ^ t) * 8);
    voff8[t] = (g ^ t) * 8;
  }

  float o[32];
#pragma unroll
  for (int i = 0; i < 32; ++i) o[i] = 0.f;

#pragma unroll 1
  for (int chunk = 0; chunk < 64; ++chunk) {
    __syncthreads();   // prev phase-2 done before restaging K/V
    const int i0 = chunk * 16;
    for (int s = tid; s < 1024; s += 256) {
      const int r = s >> 6, gg = s & 63;
      const size_t goff = ((size_t)(b * 1024 + i0 + r) * 512) + gg * 8;
      const int4 kraw = *(const int4*)(Km + goff);
      const int4 vraw = *(const int4*)(Vm + goff);
      const int sw = (gg ^ (r & 7)) * 8;
      *(int4*)(Ks + r * 512 + sw) = kraw;
      *(int4*)(Vs + r * 512 + sw) = vraw;
    }
    __syncthreads();

    // ---- phase 1: lane=(quad=query, key); fp32 L1 distance per head
    float d8[8];
#pragma unroll
    for (int h = 0; h < 8; ++h) d8[h] = 0.f;

#pragma unroll
    for (int ghi = 0; ghi < 8; ++ghi) {
#pragma unroll
      for (int glo = 0; glo < 8; ++glo) {
        const int4 kv = *(const int4*)(Ks + koff8[glo] + ghi * 64);
        const int4 qv = *(const int4*)(Qs + qoff8[glo] + ghi * 64);
        const u16* ku = reinterpret_cast<const u16*>(&kv);
        const u16* qu = reinterpret_cast<const u16*>(&qv);
#pragma unroll
        for (int e = 0; e < 8; ++e)
          d8[e] += fabsf(bf2f(ku[e]) - bf2f(qu[e]));
      }
    }

    float p[8];
#pragma unroll
    for (int h = 0; h < 8; ++h) p[h] = d8[h] * d8[h];
    float m = p[0];
#pragma unroll
    for (int h = 1; h < 8; ++h) m = fminf(m, p[h]);
    float w[8], norm = 0.f;
#pragma unroll
    for (int h = 0; h < 8; ++h) { w[h] = __expf(0.5f * (m - p[h])); norm += w[h]; }
    const float inv = 1.0f / norm;   // norm >= 1 always (min head contributes 1)
    float4 w0 = make_float4(w[0] * inv, w[1] * inv, w[2] * inv, w[3] * inv);
    float4 w1 = make_float4(w[4] * inv, w[5] * inv, w[6] * inv, w[7] * inv);
    *(float4*)&attn_s[(q_local * 16 + key) * 8] = w0;
    *(float4*)&attn_s[(q_local * 16 + key) * 8 + 4] = w1;

    __syncthreads();

    // ---- phase 2: lane = feature granule; accumulate 4 queries x 8 feats
#pragma unroll
    for (int k2 = 0; k2 < 16; ++k2) {
      const int4 vv = *(const int4*)(Vs + voff8[k2 & 7] + k2 * 512);
      const u16* vu = reinterpret_cast<const u16*>(&vv);
      float vf[8];
#pragma unroll
      for (int t = 0; t < 8; ++t) vf[t] = bf2f(vu[t]);
#pragma unroll
      for (int qq = 0; qq < 4; ++qq) {
        const float4 x0 = *(const float4*)&attn_s[((wave * 4 + qq) * 16 + k2) * 8];
        const float4 x1 = *(const float4*)&attn_s[((wave * 4 + qq) * 16 + k2) * 8 + 4];
        float* oq = o + qq * 8;
        oq[0] = fmaf(x0.x, vf[0], oq[0]);
        oq[1] = fmaf(x0.y, vf[1], oq[1]);
        oq[2] = fmaf(x0.z, vf[2], oq[2]);
        oq[3] = fmaf(x0.w, vf[3], oq[3]);
        oq[4] = fmaf(x1.x, vf[4], oq[4]);
        oq[5] = fmaf(x1.y, vf[5], oq[5]);
        oq[6] = fmaf(x1.z, vf[6], oq[6]);
        oq[7] = fmaf(x1.w, vf[7], oq[7]);
      }
    }
  }

#pragma unroll
  for (int qq = 0; qq < 4; ++qq) {
    const int j = j0 + wave * 4 + qq;
    int4 pk;
    u16* pu = reinterpret_cast<u16*>(&pk);
#pragma unroll
    for (int t = 0; t < 8; ++t) pu[t] = f2bf(o[qq * 8 + t]);
    *(int4*)(out_pre + ((size_t)(b * 1024 + j) * 512) + g * 8) = pk;
  }
}

// ---------------- host ----------------
extern "C" void kernel_launch(void* const* d_in, const int* in_sizes, int n_in,
                              void* d_out, int out_size, void* d_ws, size_t ws_size,
                              hipStream_t stream) {
  (void)in_sizes; (void)n_in; (void)out_size; (void)ws_size;
  char* wsp = (char*)d_ws;
  size_t off = 0;
  auto take = [&](size_t elems) {
    u16* p = (u16*)(wsp + off);
    off += ((elems * 2 + 255) & ~(size_t)255);
    return p;
  };

  static const int wR[10] = {128, 512, 512, 128, 512, 512, 128, 512, 512, 512};
  static const int wC[10] = {512, 512, 512, 512, 512, 512, 512, 512, 512, 128};
  static const int widx[10] = {3, 5, 7, 9, 11, 13, 15, 17, 19, 21};

  u16* WT[10];
  for (int i = 0; i < 10; ++i) WT[i] = take((size_t)wR[i] * wC[i]);
  u16* h1[3]; for (int i = 0; i < 3; ++i) h1[i] = take((size_t)4096 * 512);
  u16* h2[3]; for (int i = 0; i < 3; ++i) h2[i] = take((size_t)4096 * 512);

  TransArgs ta;
  for (int i = 0; i < 10; ++i) {
    ta.src[i] = (const float*)d_in[widx[i]];
    ta.dst[i] = WT[i];
    ta.R[i] = wR[i];
    ta.C[i] = wC[i];
  }
  hipLaunchKernelGGL(transpose_k, dim3(16, 16, 10), dim3(256), 0, stream, ta);

  // layer 1: [4096x128]@[128x512]+b, relu; A fp32  (z: 0=k/KEY, 1=q/QUERY, 2=v/VALUE)
  GemmArgs g1 = {};
  g1.A[0] = d_in[0]; g1.A[1] = d_in[2]; g1.A[2] = d_in[1];
  g1.WT[0] = WT[0]; g1.WT[1] = WT[3]; g1.WT[2] = WT[6];
  g1.bias[0] = (const float*)d_in[4]; g1.bias[1] = (const float*)d_in[10]; g1.bias[2] = (const float*)d_in[16];
  g1.C[0] = h1[0]; g1.C[1] = h1[1]; g1.C[2] = h1[2];
  hipLaunchKernelGGL(gemm_bias_act, dim3(8, 64, 3), dim3(256), 0, stream, g1, 4096, 512, 128, 1, 1, 0);

  // layer 2: [4096x512]@[512x512]+b, relu; A bf16
  GemmArgs g2 = {};
  for (int i = 0; i < 3; ++i) { g2.A[i] = h1[i]; g2.C[i] = h2[i]; }
  g2.WT[0] = WT[1]; g2.WT[1] = WT[4]; g2.WT[2] = WT[7];
  g2.bias[0] = (const float*)d_in[6]; g2.bias[1] = (const float*)d_in[12]; g2.bias[2] = (const float*)d_in[18];
  hipLaunchKernelGGL(gemm_bias_act, dim3(8, 64, 3), dim3(256), 0, stream, g2, 4096, 512, 512, 1, 0, 0);

  // layer 3: [4096x512]@[512x512]+b, no act -> Km,Qm,Vm in h1[]
  GemmArgs g3 = {};
  for (int i = 0; i < 3; ++i) { g3.A[i] = h2[i]; g3.C[i] = h1[i]; }
  g3.WT[0] = WT[2]; g3.WT[1] = WT[5]; g3.WT[2] = WT[8];
  g3.bias[0] = (const float*)d_in[8]; g3.bias[1] = (const float*)d_in[14]; g3.bias[2] = (const float*)d_in[20];
  hipLaunchKernelGGL(gemm_bias_act, dim3(8, 64, 3), dim3(256), 0, stream, g3, 4096, 512, 512, 0, 0, 0);

  // fused attention -> out_pre (bf16) in h2[0]
  hipLaunchKernelGGL(attn_kernel, dim3(256), dim3(256), 0, stream, h1[0], h1[1], h1[2], h2[0]);

  // final projection: [4096x512]@[512x128]+b -> d_out (fp32)
  GemmArgs g4 = {};
  g4.A[0] = h2[0]; g4.WT[0] = WT[9]; g4.bias[0] = (const float*)d_in[22]; g4.C[0] = d_out;
  hipLaunchKernelGGL(gemm_bias_act, dim3(2, 64, 1), dim3(256), 0, stream, g4, 4096, 128, 512, 0, 0, 1);
}

// Round 3
// 416.781 us; speedup vs baseline: 1.5360x; 1.5360x over previous
//
#include <hip/hip_runtime.h>
#include <hip/hip_bf16.h>
#include <hip/hip_fp16.h>

typedef unsigned short u16;
typedef __attribute__((ext_vector_type(8))) short short8;
typedef __attribute__((ext_vector_type(4))) float floatx4;

#define DEVI static __device__ __forceinline__

DEVI float bf2f(u16 b) { return __uint_as_float(((unsigned)b) << 16); }
DEVI u16 f2bf(float f) {
  __hip_bfloat16 h = __float2bfloat16(f);
  u16 u; __builtin_memcpy(&u, &h, 2); return u;
}

// ---------------- weight transpose + fp32->bf16: dst[C][R] = bf16(src[R][C]^T) ----------------
struct TransArgs {
  const float* src[10];
  u16* dst[10];
  int R[10];
  int C[10];
};

__global__ __launch_bounds__(256) void transpose_k(TransArgs t) {
  const int z = blockIdx.z;
  const float* __restrict__ src = t.src[z];
  u16* __restrict__ dst = t.dst[z];
  const int R = t.R[z], C = t.C[z];
  const int c0 = blockIdx.x * 32, r0 = blockIdx.y * 32;
  if (c0 >= C || r0 >= R) return;
  __shared__ float tile[32][33];
  const int tx = threadIdx.x & 31, ty = threadIdx.x >> 5;
  for (int i = ty; i < 32; i += 8)
    tile[i][tx] = src[(size_t)(r0 + i) * C + c0 + tx];
  __syncthreads();
  for (int i = ty; i < 32; i += 8)
    dst[(size_t)(c0 + i) * R + r0 + tx] = f2bf(tile[tx][i]);
}

// ------------- GEMM: C[M][N] = act(A[M][K] @ W + bias), WT[N][K] bf16 given -------------
struct GemmArgs {
  const void* A[3];      // fp32 if a_f32 else bf16
  const u16* WT[3];      // bf16
  const float* bias[3];  // fp32
  void* C[3];            // fp32 if c_f32 else bf16
};

__global__ __launch_bounds__(256) void gemm_bias_act(GemmArgs ga, int M, int N, int K,
                                                     int relu, int a_f32, int c_f32) {
  const int z = blockIdx.z;
  const void* __restrict__ A = ga.A[z];
  const u16* __restrict__ WT = ga.WT[z];
  const float* __restrict__ bias = ga.bias[z];
  void* __restrict__ C = ga.C[z];

  __shared__ u16 As[64][72];
  __shared__ u16 Bs[64][72];

  const int tid = threadIdx.x;
  const int lane = tid & 63;
  const int wave = tid >> 6;
  const int wm = wave >> 1, wn = wave & 1;
  const int mb = blockIdx.y, nb = blockIdx.x;

  floatx4 acc0 = {0.f, 0.f, 0.f, 0.f}, acc1 = acc0, acc2 = acc0, acc3 = acc0;

  const int sr = tid >> 3;        // 0..31
  const int sc = (tid & 7) * 8;   // 0..56

  for (int k0 = 0; k0 < K; k0 += 64) {
    __syncthreads();
#pragma unroll
    for (int it = 0; it < 2; ++it) {
      const int rr = sr + it * 32;
      if (a_f32) {
        const float* Af = (const float*)A;
        const float4 f0 = *(const float4*)(Af + (size_t)(mb * 64 + rr) * K + k0 + sc);
        const float4 f1 = *(const float4*)(Af + (size_t)(mb * 64 + rr) * K + k0 + sc + 4);
        u16 tmp[8] = {f2bf(f0.x), f2bf(f0.y), f2bf(f0.z), f2bf(f0.w),
                      f2bf(f1.x), f2bf(f1.y), f2bf(f1.z), f2bf(f1.w)};
        int4 t; __builtin_memcpy(&t, tmp, 16);
        *(int4*)&As[rr][sc] = t;
      } else {
        const u16* Ab = (const u16*)A;
        *(int4*)&As[rr][sc] = *(const int4*)(Ab + (size_t)(mb * 64 + rr) * K + k0 + sc);
      }
      *(int4*)&Bs[rr][sc] = *(const int4*)(WT + (size_t)(nb * 64 + rr) * K + k0 + sc);
    }
    __syncthreads();
#pragma unroll
    for (int ks = 0; ks < 2; ++ks) {
      const int koff = ks * 32 + (lane >> 4) * 8;
      const int am = wm * 32 + (lane & 15);
      const int bn = wn * 32 + (lane & 15);
      short8 a0 = *(const short8*)&As[am][koff];
      short8 a1 = *(const short8*)&As[am + 16][koff];
      short8 b0 = *(const short8*)&Bs[bn][koff];
      short8 b1 = *(const short8*)&Bs[bn + 16][koff];
      acc0 = __builtin_amdgcn_mfma_f32_16x16x32_bf16(a0, b0, acc0, 0, 0, 0);
      acc1 = __builtin_amdgcn_mfma_f32_16x16x32_bf16(a0, b1, acc1, 0, 0, 0);
      acc2 = __builtin_amdgcn_mfma_f32_16x16x32_bf16(a1, b0, acc2, 0, 0, 0);
      acc3 = __builtin_amdgcn_mfma_f32_16x16x32_bf16(a1, b1, acc3, 0, 0, 0);
    }
  }

  const int colb = nb * 64 + wn * 32 + (lane & 15);
  const int rowb = mb * 64 + wm * 32 + (lane >> 4) * 4;
  const floatx4 accs[4] = {acc0, acc1, acc2, acc3};
#pragma unroll
  for (int mg = 0; mg < 2; ++mg) {
#pragma unroll
    for (int ng = 0; ng < 2; ++ng) {
      const int col = colb + ng * 16;
      const float bv = bias[col];
      const floatx4 v = accs[mg * 2 + ng];
#pragma unroll
      for (int r = 0; r < 4; ++r) {
        const int row = rowb + mg * 16 + r;
        float x = v[r] + bv;
        if (relu) x = fmaxf(x, 0.f);
        if (c_f32) ((float*)C)[(size_t)row * N + col] = x;
        else       ((u16*)C)[(size_t)row * N + col] = f2bf(x);
      }
    }
  }
}

// ---------------- fused attention, key-split x2, packed fp16 ----------------
// partial[sp][b,j,f] = sum_{i in split} softmax_h(-0.5*d8^2)[f%8] * V[b,i,f]
DEVI int4 bf8_to_h8(int4 raw) {
  const u16* u = reinterpret_cast<const u16*>(&raw);
  int4 out;
  __half* h = reinterpret_cast<__half*>(&out);
#pragma unroll
  for (int i = 0; i < 8; ++i)
    h[i] = __float2half(__uint_as_float(((unsigned)u[i]) << 16));  // bf16->fp16 exact
  return out;
}

__global__ __launch_bounds__(256) void attn_kernel(const u16* __restrict__ Km,
                                                   const u16* __restrict__ Qm,
                                                   const u16* __restrict__ Vm,
                                                   float* __restrict__ partial) {
  __shared__ alignas(16) u16 Qs[16 * 512];            // fp16
  __shared__ alignas(16) u16 Ks[16 * 512];            // fp16
  __shared__ alignas(16) u16 Vs[16 * 512];            // fp16
  __shared__ alignas(16) u16 attn_h[16 * 16 * 8];     // fp16 [q][key][h]

  const int tid = threadIdx.x;
  const int lane = tid & 63;
  const int wave = tid >> 6;
  const int bid = blockIdx.x;      // qt(6) | sp(1) | b(2)
  const int qt = bid & 63;
  const int sp = (bid >> 6) & 1;
  const int b = bid >> 7;
  const int j0 = qt * 16;

  // stage 16 Q rows once: bf16 -> fp16, XOR-swizzled 16B granules
  for (int s = tid; s < 1024; s += 256) {
    const int r = s >> 6, gg = s & 63;
    const int4 raw = *(const int4*)(Qm + ((size_t)(b * 1024 + j0 + r) * 512) + gg * 8);
    *(int4*)(Qs + r * 512 + ((gg ^ (r & 7)) * 8)) = bf8_to_h8(raw);
  }

  const int key = lane & 15;
  const int quad = lane >> 4;
  const int q_local = wave * 4 + quad;
  const int ksw = key & 7;
  const int qsw = q_local & 7;
  const int g = lane;              // phase-2 feature granule

  int koff8[8], qoff8[8], voff8[8];
#pragma unroll
  for (int t = 0; t < 8; ++t) {
    koff8[t] = key * 512 + ((ksw ^ t) * 8);
    qoff8[t] = q_local * 512 + ((qsw ^ t) * 8);
    voff8[t] = (g ^ t) * 8;
  }

  float o[32];
#pragma unroll
  for (int i = 0; i < 32; ++i) o[i] = 0.f;

#pragma unroll 1
  for (int chunk = 0; chunk < 32; ++chunk) {
    __syncthreads();   // prev phase-2 done before restaging K/V
    const int i0 = sp * 512 + chunk * 16;
    for (int s = tid; s < 1024; s += 256) {
      const int r = s >> 6, gg = s & 63;
      const size_t goff = ((size_t)(b * 1024 + i0 + r) * 512) + gg * 8;
      const int4 kraw = *(const int4*)(Km + goff);
      const int4 vraw = *(const int4*)(Vm + goff);
      const int sw = (gg ^ (r & 7)) * 8;
      *(int4*)(Ks + r * 512 + sw) = bf8_to_h8(kraw);
      *(int4*)(Vs + r * 512 + sw) = bf8_to_h8(vraw);
    }
    __syncthreads();

    // ---- phase 1: lane=(quad=query, key); packed fp16 L1, fp32 promote /16 terms
    float d8[8];
#pragma unroll
    for (int h = 0; h < 8; ++h) d8[h] = 0.f;

#pragma unroll
    for (int gb = 0; gb < 4; ++gb) {
      __half2 a0 = __float2half2_rn(0.f), a1 = a0, a2 = a0, a3 = a0;
#pragma unroll
      for (int gh = 0; gh < 2; ++gh) {
        const int ghi = gb * 2 + gh;
#pragma unroll
        for (int glo = 0; glo < 8; ++glo) {
          const int4 kv = *(const int4*)(Ks + koff8[glo] + ghi * 64);
          const int4 qv = *(const int4*)(Qs + qoff8[glo] + ghi * 64);
          const __half2* kh = reinterpret_cast<const __half2*>(&kv);
          const __half2* qh = reinterpret_cast<const __half2*>(&qv);
          a0 = __hadd2(a0, __habs2(__hsub2(kh[0], qh[0])));
          a1 = __hadd2(a1, __habs2(__hsub2(kh[1], qh[1])));
          a2 = __hadd2(a2, __habs2(__hsub2(kh[2], qh[2])));
          a3 = __hadd2(a3, __habs2(__hsub2(kh[3], qh[3])));
        }
      }
      const float2 f0 = __half22float2(a0), f1 = __half22float2(a1);
      const float2 f2 = __half22float2(a2), f3 = __half22float2(a3);
      d8[0] += f0.x; d8[1] += f0.y; d8[2] += f1.x; d8[3] += f1.y;
      d8[4] += f2.x; d8[5] += f2.y; d8[6] += f3.x; d8[7] += f3.y;
    }

    float p[8];
#pragma unroll
    for (int h = 0; h < 8; ++h) p[h] = d8[h] * d8[h];
    float m = p[0];
#pragma unroll
    for (int h = 1; h < 8; ++h) m = fminf(m, p[h]);
    float w[8], norm = 0.f;
#pragma unroll
    for (int h = 0; h < 8; ++h) { w[h] = __expf(0.5f * (m - p[h])); norm += w[h]; }
    const float inv = 1.0f / norm;   // norm >= 1
    int4 wpack;
    __half2* wh = reinterpret_cast<__half2*>(&wpack);
    wh[0] = __floats2half2_rn(w[0] * inv, w[1] * inv);
    wh[1] = __floats2half2_rn(w[2] * inv, w[3] * inv);
    wh[2] = __floats2half2_rn(w[4] * inv, w[5] * inv);
    wh[3] = __floats2half2_rn(w[6] * inv, w[7] * inv);
    *(int4*)&attn_h[(q_local * 16 + key) * 8] = wpack;
    // no barrier: attn_h producer/consumer lanes are in the SAME wave

    // ---- phase 2: lane = feature granule; packed fp16 FMA, promote per chunk
    __half2 oa[4][4];
#pragma unroll
    for (int q = 0; q < 4; ++q)
#pragma unroll
      for (int i = 0; i < 4; ++i) oa[q][i] = __float2half2_rn(0.f);

#pragma unroll
    for (int k2 = 0; k2 < 16; ++k2) {
      const int4 vv = *(const int4*)(Vs + voff8[k2 & 7] + k2 * 512);
      const __half2* vh = reinterpret_cast<const __half2*>(&vv);
#pragma unroll
      for (int q = 0; q < 4; ++q) {
        const int4 av = *(const int4*)&attn_h[((wave * 4 + q) * 16 + k2) * 8];
        const __half2* ah = reinterpret_cast<const __half2*>(&av);
        oa[q][0] = __hfma2(ah[0], vh[0], oa[q][0]);
        oa[q][1] = __hfma2(ah[1], vh[1], oa[q][1]);
        oa[q][2] = __hfma2(ah[2], vh[2], oa[q][2]);
        oa[q][3] = __hfma2(ah[3], vh[3], oa[q][3]);
      }
    }
#pragma unroll
    for (int q = 0; q < 4; ++q)
#pragma unroll
      for (int i = 0; i < 4; ++i) {
        const float2 f = __half22float2(oa[q][i]);
        o[q * 8 + i * 2] += f.x;
        o[q * 8 + i * 2 + 1] += f.y;
      }
  }

  // write fp32 partial sums
#pragma unroll
  for (int q = 0; q < 4; ++q) {
    const int j = j0 + wave * 4 + q;
    float* dst = partial + ((size_t)sp * 4096 + b * 1024 + j) * 512 + g * 8;
    *(float4*)dst = make_float4(o[q * 8 + 0], o[q * 8 + 1], o[q * 8 + 2], o[q * 8 + 3]);
    *(float4*)(dst + 4) = make_float4(o[q * 8 + 4], o[q * 8 + 5], o[q * 8 + 6], o[q * 8 + 7]);
  }
}

// ---------------- reduce: out_pre = bf16(p0 + p1) ----------------
__global__ __launch_bounds__(256) void reduce_k(const float* __restrict__ p,
                                                u16* __restrict__ out) {
  const size_t i = (size_t)blockIdx.x * 256 + threadIdx.x;   // granule of 8
  const float4 a0 = *(const float4*)(p + i * 8);
  const float4 a1 = *(const float4*)(p + i * 8 + 4);
  const float4 b0 = *(const float4*)(p + 2097152 + i * 8);
  const float4 b1 = *(const float4*)(p + 2097152 + i * 8 + 4);
  int4 pk;
  u16* pu = reinterpret_cast<u16*>(&pk);
  pu[0] = f2bf(a0.x + b0.x); pu[1] = f2bf(a0.y + b0.y);
  pu[2] = f2bf(a0.z + b0.z); pu[3] = f2bf(a0.w + b0.w);
  pu[4] = f2bf(a1.x + b1.x); pu[5] = f2bf(a1.y + b1.y);
  pu[6] = f2bf(a1.z + b1.z); pu[7] = f2bf(a1.w + b1.w);
  *(int4*)(out + i * 8) = pk;
}

// ---------------- host ----------------
extern "C" void kernel_launch(void* const* d_in, const int* in_sizes, int n_in,
                              void* d_out, int out_size, void* d_ws, size_t ws_size,
                              hipStream_t stream) {
  (void)in_sizes; (void)n_in; (void)out_size; (void)ws_size;
  char* wsp = (char*)d_ws;
  size_t off = 0;
  auto take = [&](size_t bytes) {
    void* p = (void*)(wsp + off);
    off += ((bytes + 255) & ~(size_t)255);
    return p;
  };

  static const int wR[10] = {128, 512, 512, 128, 512, 512, 128, 512, 512, 512};
  static const int wC[10] = {512, 512, 512, 512, 512, 512, 512, 512, 512, 128};
  static const int widx[10] = {3, 5, 7, 9, 11, 13, 15, 17, 19, 21};

  u16* WT[10];
  for (int i = 0; i < 10; ++i) WT[i] = (u16*)take((size_t)wR[i] * wC[i] * 2);
  u16* h1[3]; for (int i = 0; i < 3; ++i) h1[i] = (u16*)take((size_t)4096 * 512 * 2);
  u16* h2[3]; for (int i = 0; i < 3; ++i) h2[i] = (u16*)take((size_t)4096 * 512 * 2);
  float* partial = (float*)take((size_t)2 * 4096 * 512 * 4);

  TransArgs ta;
  for (int i = 0; i < 10; ++i) {
    ta.src[i] = (const float*)d_in[widx[i]];
    ta.dst[i] = WT[i];
    ta.R[i] = wR[i];
    ta.C[i] = wC[i];
  }
  hipLaunchKernelGGL(transpose_k, dim3(16, 16, 10), dim3(256), 0, stream, ta);

  // layer 1: [4096x128]@[128x512]+b, relu; A fp32  (z: 0=k/KEY, 1=q/QUERY, 2=v/VALUE)
  GemmArgs g1 = {};
  g1.A[0] = d_in[0]; g1.A[1] = d_in[2]; g1.A[2] = d_in[1];
  g1.WT[0] = WT[0]; g1.WT[1] = WT[3]; g1.WT[2] = WT[6];
  g1.bias[0] = (const float*)d_in[4]; g1.bias[1] = (const float*)d_in[10]; g1.bias[2] = (const float*)d_in[16];
  g1.C[0] = h1[0]; g1.C[1] = h1[1]; g1.C[2] = h1[2];
  hipLaunchKernelGGL(gemm_bias_act, dim3(8, 64, 3), dim3(256), 0, stream, g1, 4096, 512, 128, 1, 1, 0);

  // layer 2: [4096x512]@[512x512]+b, relu; A bf16
  GemmArgs g2 = {};
  for (int i = 0; i < 3; ++i) { g2.A[i] = h1[i]; g2.C[i] = h2[i]; }
  g2.WT[0] = WT[1]; g2.WT[1] = WT[4]; g2.WT[2] = WT[7];
  g2.bias[0] = (const float*)d_in[6]; g2.bias[1] = (const float*)d_in[12]; g2.bias[2] = (const float*)d_in[18];
  hipLaunchKernelGGL(gemm_bias_act, dim3(8, 64, 3), dim3(256), 0, stream, g2, 4096, 512, 512, 1, 0, 0);

  // layer 3: [4096x512]@[512x512]+b, no act -> Km,Qm,Vm in h1[]
  GemmArgs g3 = {};
  for (int i = 0; i < 3; ++i) { g3.A[i] = h2[i]; g3.C[i] = h1[i]; }
  g3.WT[0] = WT[2]; g3.WT[1] = WT[5]; g3.WT[2] = WT[8];
  g3.bias[0] = (const float*)d_in[8]; g3.bias[1] = (const float*)d_in[14]; g3.bias[2] = (const float*)d_in[20];
  hipLaunchKernelGGL(gemm_bias_act, dim3(8, 64, 3), dim3(256), 0, stream, g3, 4096, 512, 512, 0, 0, 0);

  // fused attention (2-way key split) -> fp32 partials
  hipLaunchKernelGGL(attn_kernel, dim3(512), dim3(256), 0, stream, h1[0], h1[1], h1[2], partial);

  // reduce partials -> out_pre (bf16) in h2[0]
  hipLaunchKernelGGL(reduce_k, dim3(1024), dim3(256), 0, stream, partial, h2[0]);

  // final projection: [4096x512]@[512x128]+b -> d_out (fp32)
  GemmArgs g4 = {};
  g4.A[0] = h2[0]; g4.WT[0] = WT[9]; g4.bias[0] = (const float*)d_in[22]; g4.C[0] = d_out;
  hipLaunchKernelGGL(gemm_bias_act, dim3(2, 64, 1), dim3(256), 0, stream, g4, 4096, 128, 512, 0, 0, 1);
}